// Round 1
// baseline (900.959 us; speedup 1.0000x reference)
//
#include <hip/hip_runtime.h>
#include <hip/hip_bf16.h>

#define D_MODEL 4096
#define SHARDS 8

// Kernel 1: bsum[d] = sum_s b[s*D + d].  D/4 = 1024 float4 lanes.
__global__ __launch_bounds__(256) void bias_sum_kernel(const float* __restrict__ b,
                                                       float* __restrict__ bsum) {
    int d = blockIdx.x * blockDim.x + threadIdx.x;  // 0..1023 (float4 index)
    const float4* b4 = (const float4*)b;
    float4 acc = b4[d];
#pragma unroll
    for (int s = 1; s < SHARDS; ++s) {
        float4 v = b4[s * (D_MODEL / 4) + d];
        acc.x += v.x; acc.y += v.y; acc.z += v.z; acc.w += v.w;
    }
    ((float4*)bsum)[d] = acc;
}

// Kernel 2: one block per token. 256 threads x 4 float4 = 4096 floats = one row.
__global__ __launch_bounds__(256) void gather_bias_kernel(const int* __restrict__ tok,
                                                          const float* __restrict__ W,
                                                          const float* __restrict__ bsum,
                                                          float* __restrict__ out) {
    const int t = blockIdx.x;
    const int row = tok[t];  // wave-uniform scalar load (broadcast)
    const float4* __restrict__ Wrow = (const float4*)(W + (long long)row * D_MODEL);
    const float4* __restrict__ bs4  = (const float4*)bsum;
    float4* __restrict__ out4       = (float4*)(out + (long long)t * D_MODEL);
    const int tid = threadIdx.x;
#pragma unroll
    for (int i = 0; i < 4; ++i) {
        const int idx = tid + i * 256;   // coalesced: consecutive lanes -> consecutive float4
        float4 w = Wrow[idx];
        const float4 bb = bs4[idx];      // L2-resident (16 KiB total)
        w.x += bb.x; w.y += bb.y; w.z += bb.z; w.w += bb.w;
        out4[idx] = w;
    }
}

extern "C" void kernel_launch(void* const* d_in, const int* in_sizes, int n_in,
                              void* d_out, int out_size, void* d_ws, size_t ws_size,
                              hipStream_t stream) {
    const int*   tok = (const int*)d_in[0];    // x, int32, T elements
    const float* W   = (const float*)d_in[1];  // [50400, 4096] fp32
    const float* b   = (const float*)d_in[2];  // [8, 4096] fp32
    float* out  = (float*)d_out;               // [T, 4096] fp32
    float* bsum = (float*)d_ws;                // 4096 floats scratch

    const int T = in_sizes[0];                 // 4096 tokens

    bias_sum_kernel<<<(D_MODEL / 4) / 256, 256, 0, stream>>>(b, bsum);
    gather_bias_kernel<<<T, 256, 0, stream>>>(tok, W, bsum, out);
}

// Round 2
// 899.693 us; speedup vs baseline: 1.0014x; 1.0014x over previous
//
#include <hip/hip_runtime.h>
#include <hip/hip_bf16.h>

#define D_MODEL 4096
#define SHARDS 8
#define TPB 4  // tokens per block

// One fused kernel: out[t,d] = W[tok[t],d] + sum_s b[s,d].
// Block = 256 threads; each thread owns 4 float4 slots of the 4096-wide row.
// Bias sum computed straight into registers (b is 128 KiB -> L2-hot after the
// first blocks; 1024 blocks x 128 KiB = 128 MB of L2 reads ~ 4 us aggregate,
// overlapped with the HBM row streaming). No LDS, no second kernel, no d_ws.
__global__ __launch_bounds__(256) void embed_fused_kernel(const int* __restrict__ tok,
                                                          const float* __restrict__ W,
                                                          const float* __restrict__ b,
                                                          float* __restrict__ out,
                                                          int T) {
    const int tid = threadIdx.x;
    const int t0  = blockIdx.x * TPB;

    // Prefetch this block's 4 token ids as one 16B load (block-uniform -> scalar).
    int rows[TPB];
    if (t0 + TPB <= T) {
        const int4 r4 = ((const int4*)tok)[blockIdx.x];
        rows[0] = r4.x; rows[1] = r4.y; rows[2] = r4.z; rows[3] = r4.w;
    } else {
#pragma unroll
        for (int j = 0; j < TPB; ++j) rows[j] = (t0 + j < T) ? tok[t0 + j] : 0;
    }

    // Per-thread bias sums for its 4 slots: bb[i] = sum_s b[s, tid + i*256 (f4)]
    const float4* __restrict__ b4 = (const float4*)b;
    float4 bb[4];
#pragma unroll
    for (int i = 0; i < 4; ++i) {
        const int d = tid + i * 256;            // float4 index in [0,1024)
        float4 acc = b4[d];
#pragma unroll
        for (int s = 1; s < SHARDS; ++s) {
            const float4 v = b4[s * (D_MODEL / 4) + d];
            acc.x += v.x; acc.y += v.y; acc.z += v.z; acc.w += v.w;
        }
        bb[i] = acc;
    }

    // Stream 4 rows: gather W row, add bias, store. All float4, fully coalesced.
#pragma unroll
    for (int j = 0; j < TPB; ++j) {
        const int t = t0 + j;
        if (t >= T) break;
        const float4* __restrict__ Wrow = (const float4*)(W + (long long)rows[j] * D_MODEL);
        float4* __restrict__ out4       = (float4*)(out + (long long)t * D_MODEL);
#pragma unroll
        for (int i = 0; i < 4; ++i) {
            const int idx = tid + i * 256;
            float4 w = Wrow[idx];
            w.x += bb[i].x; w.y += bb[i].y; w.z += bb[i].z; w.w += bb[i].w;
            out4[idx] = w;
        }
    }
}

extern "C" void kernel_launch(void* const* d_in, const int* in_sizes, int n_in,
                              void* d_out, int out_size, void* d_ws, size_t ws_size,
                              hipStream_t stream) {
    const int*   tok = (const int*)d_in[0];    // x, int32, T elements
    const float* W   = (const float*)d_in[1];  // [50400, 4096] fp32
    const float* b   = (const float*)d_in[2];  // [8, 4096] fp32
    float* out = (float*)d_out;                // [T, 4096] fp32

    const int T = in_sizes[0];                 // 4096 tokens
    const int grid = (T + TPB - 1) / TPB;      // 1024 blocks -> 16 waves/CU

    embed_fused_kernel<<<grid, 256, 0, stream>>>(tok, W, b, out, T);
}